// Round 1
// baseline (1007.873 us; speedup 1.0000x reference)
//
#include <hip/hip_runtime.h>
#include <cstdint>
#include <cstddef>

#define NSEG 64
#define NCH 16
#define ALPHA 1.0f
#define BETA 1.0f
#define GAMMA 0.001f
#define DELTA_D 1.5f
// DELTA_V == 0.0

// ws layout (floats):
//   [0,1024)      gsums[c][l]   (c-major, 16x64)
//   [1024,1088)   gcounts[64]   (as unsigned)
//   [1088,1152)   gper[64]
//   [1152,2176)   gmeans[c][l]
//   [2176,2180)   scalars: [0]=K, [1]=partial(ext+nrm)
//   byte offset 16384: segs[P] (uchar), if ws_size permits

__global__ __launch_bounds__(256) void init_kernel(float* __restrict__ ws) {
    int i = blockIdx.x * 256 + threadIdx.x;
    if (i < 4096) ws[i] = 0.f;
}

__global__ __launch_bounds__(256) void pass1_kernel(
    const float* __restrict__ embd, const int* __restrict__ trgt,
    const int* __restrict__ mask, float* __restrict__ gsums,
    unsigned int* __restrict__ gcounts, unsigned char* __restrict__ segs,
    int P)
{
    __shared__ float lsums[NCH * NSEG];
    __shared__ unsigned int lcounts[NSEG];
    for (int i = threadIdx.x; i < NCH * NSEG; i += 256) lsums[i] = 0.f;
    if (threadIdx.x < NSEG) lcounts[threadIdx.x] = 0u;
    __syncthreads();

    const int P4 = P >> 2;
    const size_t stride = (size_t)gridDim.x * 256;
    const float4* __restrict__ embd4 = (const float4*)embd;
    const int4* __restrict__ trgt4 = (const int4*)trgt;
    const int4* __restrict__ mask4 = (const int4*)mask;

    for (size_t p4 = (size_t)blockIdx.x * 256 + threadIdx.x; p4 < (size_t)P4; p4 += stride) {
        int4 t = trgt4[p4];
        int4 m = mask4[p4];
        int s0 = (m.x > 0) ? t.x : 0;
        int s1 = (m.y > 0) ? t.y : 0;
        int s2 = (m.z > 0) ? t.z : 0;
        int s3 = (m.w > 0) ? t.w : 0;
        if (segs) {
            uchar4 pk;
            pk.x = (unsigned char)s0; pk.y = (unsigned char)s1;
            pk.z = (unsigned char)s2; pk.w = (unsigned char)s3;
            ((uchar4*)segs)[p4] = pk;
        }
        if (s0) atomicAdd(&lcounts[s0], 1u);
        if (s1) atomicAdd(&lcounts[s1], 1u);
        if (s2) atomicAdd(&lcounts[s2], 1u);
        if (s3) atomicAdd(&lcounts[s3], 1u);
        if ((s0 | s1 | s2 | s3) != 0) {
            #pragma unroll
            for (int c = 0; c < NCH; ++c) {
                float4 v = embd4[(size_t)c * P4 + p4];
                if (s0) atomicAdd(&lsums[c * NSEG + s0], v.x);
                if (s1) atomicAdd(&lsums[c * NSEG + s1], v.y);
                if (s2) atomicAdd(&lsums[c * NSEG + s2], v.z);
                if (s3) atomicAdd(&lsums[c * NSEG + s3], v.w);
            }
        }
    }
    // scalar tail (P % 4 != 0) — no-op for this problem
    for (size_t p = (size_t)(P4 << 2) + blockIdx.x * 256 + threadIdx.x; p < (size_t)P; p += stride) {
        int s = (mask[p] > 0) ? trgt[p] : 0;
        if (segs) segs[p] = (unsigned char)s;
        if (s) {
            atomicAdd(&lcounts[s], 1u);
            #pragma unroll
            for (int c = 0; c < NCH; ++c)
                atomicAdd(&lsums[c * NSEG + s], embd[(size_t)c * P + p]);
        }
    }
    __syncthreads();
    for (int i = threadIdx.x; i < NCH * NSEG; i += 256) {
        float v = lsums[i];
        if (v != 0.f) atomicAdd(&gsums[i], v);
    }
    if (threadIdx.x < NSEG) {
        unsigned int v = lcounts[threadIdx.x];
        if (v) atomicAdd(&gcounts[threadIdx.x], v);
    }
}

__global__ __launch_bounds__(256) void mid_kernel(
    const float* __restrict__ gsums, const unsigned int* __restrict__ gcounts,
    float* __restrict__ gmeans, float* __restrict__ scalars)
{
    __shared__ float smeans[NCH * NSEG];
    __shared__ float scnt[NSEG];
    __shared__ float s_ext, s_nrm;
    int tid = threadIdx.x;
    if (tid == 0) { s_ext = 0.f; s_nrm = 0.f; }
    if (tid < NSEG) scnt[tid] = (float)gcounts[tid];
    __syncthreads();
    for (int i = tid; i < NCH * NSEG; i += 256) {
        int l = i & (NSEG - 1);
        float mean = gsums[i] / fmaxf(scnt[l], 1.f);
        smeans[i] = mean;
        gmeans[i] = mean;
    }
    __syncthreads();
    if (tid < NSEG) {
        int l = tid;
        if (l != 0 && scnt[l] > 0.f) {
            float a = 0.f;
            #pragma unroll
            for (int c = 0; c < NCH; ++c) a += fabsf(smeans[c * NSEG + l]);
            atomicAdd(&s_nrm, a);
        }
    }
    float eacc = 0.f;
    for (int q = tid; q < NSEG * NSEG; q += 256) {
        int l1 = q >> 6, l2 = q & 63;
        if (l1 != l2 && l1 != 0 && l2 != 0 && scnt[l1] > 0.f && scnt[l2] > 0.f) {
            float d = 0.f;
            #pragma unroll
            for (int c = 0; c < NCH; ++c)
                d += fabsf(smeans[c * NSEG + l1] - smeans[c * NSEG + l2]);
            float mm = fmaxf(2.f * DELTA_D - d, 0.f);
            eacc += mm * mm;
        }
    }
    if (eacc != 0.f) atomicAdd(&s_ext, eacc);
    __syncthreads();
    if (tid == 0) {
        float K = 0.f;
        for (int l = 1; l < NSEG; ++l) if (scnt[l] > 0.f) K += 1.f;
        scalars[0] = K;
        scalars[1] = BETA * s_ext / fmaxf(1.f, K * (K - 1.f))
                   + GAMMA * s_nrm / fmaxf(1.f, K);
    }
}

__global__ __launch_bounds__(256) void pass2_kernel(
    const float* __restrict__ embd, const unsigned char* __restrict__ segs,
    const int* __restrict__ trgt, const int* __restrict__ mask,
    const float* __restrict__ gmeans, float* __restrict__ gper, int P)
{
    __shared__ float lmeans[NCH * NSEG];
    __shared__ float lper[NSEG];
    for (int i = threadIdx.x; i < NCH * NSEG; i += 256) lmeans[i] = gmeans[i];
    if (threadIdx.x < NSEG) lper[threadIdx.x] = 0.f;
    __syncthreads();

    const int P4 = P >> 2;
    const size_t stride = (size_t)gridDim.x * 256;
    const float4* __restrict__ embd4 = (const float4*)embd;

    for (size_t p4 = (size_t)blockIdx.x * 256 + threadIdx.x; p4 < (size_t)P4; p4 += stride) {
        int s0, s1, s2, s3;
        if (segs) {
            uchar4 pk = ((const uchar4*)segs)[p4];
            s0 = pk.x; s1 = pk.y; s2 = pk.z; s3 = pk.w;
        } else {
            int4 t = ((const int4*)trgt)[p4];
            int4 m = ((const int4*)mask)[p4];
            s0 = (m.x > 0) ? t.x : 0;
            s1 = (m.y > 0) ? t.y : 0;
            s2 = (m.z > 0) ? t.z : 0;
            s3 = (m.w > 0) ? t.w : 0;
        }
        if ((s0 | s1 | s2 | s3) != 0) {
            float a0 = 0.f, a1 = 0.f, a2 = 0.f, a3 = 0.f;
            #pragma unroll
            for (int c = 0; c < NCH; ++c) {
                float4 v = embd4[(size_t)c * P4 + p4];
                const float* mrow = &lmeans[c * NSEG];
                a0 += fabsf(v.x - mrow[s0]);
                a1 += fabsf(v.y - mrow[s1]);
                a2 += fabsf(v.z - mrow[s2]);
                a3 += fabsf(v.w - mrow[s3]);
            }
            if (s0) { float h = fmaxf(a0, 0.f); atomicAdd(&lper[s0], h * h); }
            if (s1) { float h = fmaxf(a1, 0.f); atomicAdd(&lper[s1], h * h); }
            if (s2) { float h = fmaxf(a2, 0.f); atomicAdd(&lper[s2], h * h); }
            if (s3) { float h = fmaxf(a3, 0.f); atomicAdd(&lper[s3], h * h); }
        }
    }
    // scalar tail — no-op for this problem
    for (size_t p = (size_t)(P4 << 2) + blockIdx.x * 256 + threadIdx.x; p < (size_t)P; p += stride) {
        int s = segs ? (int)segs[p] : ((mask[p] > 0) ? trgt[p] : 0);
        if (s) {
            float a = 0.f;
            #pragma unroll
            for (int c = 0; c < NCH; ++c)
                a += fabsf(embd[(size_t)c * P + p] - lmeans[c * NSEG + s]);
            float h = fmaxf(a, 0.f);
            atomicAdd(&lper[s], h * h);
        }
    }
    __syncthreads();
    if (threadIdx.x < NSEG) {
        float v = lper[threadIdx.x];
        if (v != 0.f) atomicAdd(&gper[threadIdx.x], v);
    }
}

__global__ __launch_bounds__(64) void final_kernel(
    const float* __restrict__ gper, const unsigned int* __restrict__ gcounts,
    const float* __restrict__ scalars, float* __restrict__ out)
{
    int l = threadIdx.x;
    float cnt = (float)gcounts[l];
    bool present = (l != 0) && (cnt > 0.f);
    float v = present ? gper[l] / fmaxf(cnt, 1.f) : 0.f;
    #pragma unroll
    for (int off = 32; off > 0; off >>= 1) v += __shfl_down(v, off);
    if (l == 0) {
        float K = scalars[0];
        float loss_int = v / fmaxf(1.f, K);
        out[0] = ALPHA * loss_int + scalars[1];
    }
}

extern "C" void kernel_launch(void* const* d_in, const int* in_sizes, int n_in,
                              void* d_out, int out_size, void* d_ws, size_t ws_size,
                              hipStream_t stream) {
    const float* embd = (const float*)d_in[0];
    const int* trgt = (const int*)d_in[1];
    const int* mask = (const int*)d_in[2];
    const int P = in_sizes[1];  // 32*512*512

    float* ws = (float*)d_ws;
    float* gsums = ws;                       // 1024
    unsigned int* gcounts = (unsigned int*)(ws + 1024);  // 64
    float* gper = ws + 1088;                 // 64
    float* gmeans = ws + 1152;               // 1024
    float* scalars = ws + 2176;              // 2

    unsigned char* segs = nullptr;
    const size_t seg_off = 16384;
    if (ws_size >= seg_off + (size_t)P) segs = (unsigned char*)d_ws + seg_off;

    init_kernel<<<16, 256, 0, stream>>>(ws);
    pass1_kernel<<<1024, 256, 0, stream>>>(embd, trgt, mask, gsums, gcounts, segs, P);
    mid_kernel<<<1, 256, 0, stream>>>(gsums, gcounts, gmeans, scalars);
    pass2_kernel<<<1024, 256, 0, stream>>>(embd, segs, trgt, mask, gmeans, gper, P);
    final_kernel<<<1, 64, 0, stream>>>(gper, gcounts, scalars, (float*)d_out);
}